// Round 1
// baseline (44286.954 us; speedup 1.0000x reference)
//
#include <hip/hip_runtime.h>
#include <hip/hip_bf16.h>

using short8 = __attribute__((ext_vector_type(8))) short;
using f32x4  = __attribute__((ext_vector_type(4))) float;

#define DEVI __device__ __forceinline__

static constexpr int TBROWS = 64 * 512;   // B*T rows, TB-major: row = t*64 + b

DEVI float sigm_f(float x) { return 1.f / (1.f + __expf(-x)); }
DEVI float selu_f(float x) {
  return 1.0507009873554805f * (x > 0.f ? x : 1.6732632423543772f * (__expf(x) - 1.f));
}

// ---------------- MLP init: h0 (bf16) and c0 (f32), shared by all 4 LSTMs ----
__global__ __launch_bounds__(512) void arm_mlp_kernel(
    const float* __restrict__ stat,
    const float* __restrict__ Wh1, const float* __restrict__ bh1,
    const float* __restrict__ Wh2, const float* __restrict__ bh2,
    const float* __restrict__ Wh3, const float* __restrict__ bh3,
    const float* __restrict__ Wc1, const float* __restrict__ bc1,
    const float* __restrict__ Wc2, const float* __restrict__ bc2,
    const float* __restrict__ Wc3, const float* __restrict__ bc3,
    __hip_bfloat16* __restrict__ h0b, float* __restrict__ c0)
{
  __shared__ float xs[64], y1[32], y2[32];
  const int b = blockIdx.x, tid = threadIdx.x;
  if (tid < 64) xs[tid] = stat[b * 64 + tid];
  __syncthreads();
  for (int sel = 0; sel < 2; ++sel) {
    const float* W1 = sel ? Wc1 : Wh1; const float* B1 = sel ? bc1 : bh1;
    const float* W2 = sel ? Wc2 : Wh2; const float* B2 = sel ? bc2 : bh2;
    const float* W3 = sel ? Wc3 : Wh3; const float* B3 = sel ? bc3 : bh3;
    if (tid < 32) {
      float a = B1[tid];
      for (int k = 0; k < 64; ++k) a += W1[tid * 64 + k] * xs[k];
      y1[tid] = selu_f(a);
    }
    __syncthreads();
    if (tid < 32) {
      float a = B2[tid];
      for (int k = 0; k < 32; ++k) a += W2[tid * 32 + k] * y1[k];
      y2[tid] = selu_f(a);
    }
    __syncthreads();
    {
      float a = B3[tid];
      for (int k = 0; k < 32; ++k) a += W3[tid * 32 + k] * y2[k];
      a = selu_f(a);
      if (sel == 0) h0b[b * 512 + tid] = __float2bfloat16(a);
      else          c0 [b * 512 + tid] = a;
    }
    __syncthreads();
  }
}

// ---------------- Xcat: [TB][96] bf16, cols 0..63 static, 64..79 rec, 80..95 zero
__global__ __launch_bounds__(256) void arm_xcat_kernel(
    const float* __restrict__ stat, const float* __restrict__ rec,
    __hip_bfloat16* __restrict__ xc)
{
  const int total = TBROWS * 96;
  for (int i = blockIdx.x * 256 + threadIdx.x; i < total; i += gridDim.x * 256) {
    int row = i / 96, k = i - row * 96;
    int t = row >> 6, b = row & 63;
    float v = 0.f;
    if (k < 64)      v = stat[b * 64 + k];
    else if (k < 80) v = rec[((size_t)b * 512 + t) * 16 + (k - 64)];
    xc[i] = __float2bfloat16(v);
  }
}

// ---------------- f32 -> bf16 convert with K padding: dst [N][Kp]
__global__ __launch_bounds__(256) void arm_cvtpad_kernel(
    const float* __restrict__ src, __hip_bfloat16* __restrict__ dst,
    int N, int Ks, int Kp)
{
  const int total = N * Kp;
  for (int i = blockIdx.x * 256 + threadIdx.x; i < total; i += gridDim.x * 256) {
    int n = i / Kp, k = i - n * Kp;
    dst[i] = __float2bfloat16(k < Ks ? src[(size_t)n * Ks + k] : 0.f);
  }
}

__global__ __launch_bounds__(256) void arm_bsum_kernel(
    const float* __restrict__ a, const float* __restrict__ b,
    float* __restrict__ d, int n)
{
  int i = blockIdx.x * 256 + threadIdx.x;
  if (i < n) d[i] = a[i] + b[i];
}

// ---------------- fused LSTM scan ----------------
// 128 blocks: blk&1 -> batch-row half (32 rows), blk>>1 -> 8 hidden units.
// Block owns 32 gate rows (4 gates x 8 units) of [Wih | Whh] in LDS (bf16).
// Per step t: gates[32rows x 32cols] = [segs(t), h(t-1)] @ slabT via MFMA,
// then elementwise (c fp32 in LDS), write h bf16 to hseq, flag/spin sync.
#define WSL_STRIDE 1544   // 1536 + 8 bf16 pad

__global__ __launch_bounds__(256) void arm_scan_kernel(
    const __hip_bfloat16* __restrict__ seg1, int lda1, int K1,
    const __hip_bfloat16* __restrict__ seg2, int lda2, int Kp,
    const __hip_bfloat16* __restrict__ Wihp,   // [2048][Kp] bf16
    const __hip_bfloat16* __restrict__ Whhb,   // [2048][512] bf16
    const float* __restrict__ bsum,            // [2048] bih+bhh
    const __hip_bfloat16* __restrict__ h0b,    // [64][512]
    const float* __restrict__ c0,              // [64][512]
    __hip_bfloat16* __restrict__ hseq,         // [T*64][512] out
    unsigned* __restrict__ fl,                 // 128 slots, 16 u32 apart
    float* __restrict__ dh, float* __restrict__ dc)
{
  __shared__ __align__(16) __hip_bfloat16 wsl[32 * WSL_STRIDE];
  __shared__ float gbuf[32][33];
  __shared__ float cst[32][8];
  __shared__ float bs[32];

  const int tid = threadIdx.x;
  const int blk = blockIdx.x;
  const int r0 = (blk & 1) * 32;     // batch-row base
  const int u0 = (blk >> 1) * 8;     // hidden-unit base
  const int Ktot = Kp + 512;

  // stage [Wih | Whh] rows: local c -> global gate row (c>>3)*512 + u0 + (c&7)
  for (int i = tid; i < 32 * Ktot; i += 256) {
    int c = i / Ktot, k = i - c * Ktot;
    int grow = ((c >> 3) << 9) + u0 + (c & 7);
    wsl[c * WSL_STRIDE + k] =
        (k < Kp) ? Wihp[(size_t)grow * Kp + k] : Whhb[((size_t)grow << 9) + (k - Kp)];
  }
  if (tid < 32) bs[tid] = bsum[((tid >> 3) << 9) + u0 + (tid & 7)];
  { int bb = tid >> 3, u = tid & 7; cst[bb][u] = c0[(size_t)(r0 + bb) * 512 + u0 + u]; }
  __syncthreads();

  const int lane = tid & 63, wv = tid >> 6;
  const int frow = lane & 15, fk8 = ((lane >> 4) << 3);
  const int rt = wv >> 1, ct = wv & 1;           // wave -> (row-tile, col-tile)
  const int arow = rt * 16 + frow;               // local A row (0..31)
  const __hip_bfloat16* wb_base = &wsl[(ct * 16 + frow) * WSL_STRIDE];
  const int nks = Ktot >> 5;
  unsigned budget = 1u << 24;                    // spin bail-out (hang safety)

  for (int t = 0; t < 512; ++t) {
    const __hip_bfloat16* hp = t ? (hseq + ((size_t)(t - 1) * 64) * 512) : h0b;
    const size_t growA = (size_t)(t * 64 + r0 + arow);
    f32x4 acc = {0.f, 0.f, 0.f, 0.f};
    for (int ks = 0; ks < nks; ++ks) {
      const int kgu = ks << 5;
      const __hip_bfloat16* ap;
      if (kgu < K1)      ap = seg1 + growA * lda1 + kgu + fk8;
      else if (kgu < Kp) ap = seg2 + growA * lda2 + (kgu - K1) + fk8;
      else               ap = hp + (((size_t)(r0 + arow)) << 9) + (kgu - Kp) + fk8;
      short8 a = *(const short8*)ap;
      short8 b = *(const short8*)(wb_base + kgu + fk8);
      acc = __builtin_amdgcn_mfma_f32_16x16x32_bf16(a, b, acc, 0, 0, 0);
    }
    // epilogue: C row = rt*16 + (lane>>4)*4 + j, col = ct*16 + (lane&15)
    {
      const int ccol = ct * 16 + frow;
      const int crow = rt * 16 + ((lane >> 4) << 2);
      const float bb = bs[ccol];
#pragma unroll
      for (int j = 0; j < 4; ++j) gbuf[crow + j][ccol] = acc[j] + bb;
    }
    __syncthreads();
    // elementwise: one (batch-row, unit) per thread; PyTorch gate order i,f,g,o
    {
      const int bb = tid >> 3, u = tid & 7;
      float gi = gbuf[bb][u],      gf = gbuf[bb][8 + u];
      float gg = gbuf[bb][16 + u], go = gbuf[bb][24 + u];
      float cn = sigm_f(gf) * cst[bb][u] + sigm_f(gi) * tanhf(gg);
      float hn = sigm_f(go) * tanhf(cn);
      cst[bb][u] = cn;
      hseq[((size_t)(t * 64 + r0 + bb)) * 512 + u0 + u] = __float2bfloat16(hn);
      if (t == 511) {
        dh[(r0 + bb) * 512 + u0 + u] = hn;
        dc[(r0 + bb) * 512 + u0 + u] = cn;
      }
    }
    __syncthreads();   // drains vmcnt: block's hseq stores complete
    if (tid == 0) {
      __threadfence(); // device-scope release of this block's stores (L2 wb)
      __hip_atomic_store(fl + blk * 16, (unsigned)(t + 1),
                         __ATOMIC_RELEASE, __HIP_MEMORY_SCOPE_AGENT);
    }
    if (wv == 0) {
      const unsigned tgt = t + 1;
      while (budget) {
        unsigned va = __hip_atomic_load(fl + lane * 16,
                                        __ATOMIC_RELAXED, __HIP_MEMORY_SCOPE_AGENT);
        unsigned vb = __hip_atomic_load(fl + (64 + lane) * 16,
                                        __ATOMIC_RELAXED, __HIP_MEMORY_SCOPE_AGENT);
        if (__all((va >= tgt) && (vb >= tgt))) break;
        --budget;
      }
    }
    __syncthreads();
    __threadfence();   // acquire side: invalidate stale caches before reading new h
  }
}

// ---------------- final projection: out = [h3,h4] @ Wout^T + bout, sigmoid(:2)
__global__ __launch_bounds__(256) void arm_out_kernel(
    const __hip_bfloat16* __restrict__ h3b, const __hip_bfloat16* __restrict__ h4b,
    const float* __restrict__ Wout, const float* __restrict__ bout,
    float* __restrict__ out)
{
  __shared__ float w_s[16][1025];
  __shared__ __hip_bfloat16 a_s[16][1032];
  __shared__ float bo[16];
  const int tid = threadIdx.x;
  for (int i = tid; i < 16 * 1024; i += 256) {
    int n = i >> 10, k = i & 1023;
    w_s[n][k] = Wout[i];
  }
  if (tid < 16) bo[tid] = bout[tid];
  const int rb = blockIdx.x * 16;
  for (int i = tid; i < 16 * 512; i += 256) {
    int r = i >> 9, k = i & 511;
    a_s[r][k]       = h3b[(((size_t)(rb + r)) << 9) + k];
    a_s[r][512 + k] = h4b[(((size_t)(rb + r)) << 9) + k];
  }
  __syncthreads();
  const int r = tid >> 4, n = tid & 15;
  float acc = bo[n];
  for (int k = 0; k < 1024; ++k)
    acc += __bfloat162float(a_s[r][k]) * w_s[n][k];
  const int ri = rb + r, t = ri >> 6, b = ri & 63;
  if (n < 2) acc = sigm_f(acc);
  out[((size_t)(b * 512 + t)) * 16 + n] = acc;
}

extern "C" void kernel_launch(void* const* d_in, const int* in_sizes, int n_in,
                              void* d_out, int out_size, void* d_ws, size_t ws_size,
                              hipStream_t stream) {
  (void)in_sizes; (void)n_in; (void)out_size; (void)ws_size;
  const float* stat = (const float*)d_in[0];
  const float* rec  = (const float*)d_in[1];
  const float* Wh1 = (const float*)d_in[2];  const float* bh1 = (const float*)d_in[3];
  const float* Wh2 = (const float*)d_in[4];  const float* bh2 = (const float*)d_in[5];
  const float* Wh3 = (const float*)d_in[6];  const float* bh3 = (const float*)d_in[7];
  const float* Wc1 = (const float*)d_in[8];  const float* bc1 = (const float*)d_in[9];
  const float* Wc2 = (const float*)d_in[10]; const float* bc2 = (const float*)d_in[11];
  const float* Wc3 = (const float*)d_in[12]; const float* bc3 = (const float*)d_in[13];
  const float* Wih[4] = {(const float*)d_in[14], (const float*)d_in[18],
                         (const float*)d_in[22], (const float*)d_in[26]};
  const float* Whh[4] = {(const float*)d_in[15], (const float*)d_in[19],
                         (const float*)d_in[23], (const float*)d_in[27]};
  const float* bih[4] = {(const float*)d_in[16], (const float*)d_in[20],
                         (const float*)d_in[24], (const float*)d_in[28]};
  const float* bhh[4] = {(const float*)d_in[17], (const float*)d_in[21],
                         (const float*)d_in[25], (const float*)d_in[29]};
  const float* Wout = (const float*)d_in[30];
  const float* bout = (const float*)d_in[31];
  float* out = (float*)d_out;

  char* ws = (char*)d_ws;
  size_t off = 0;
  auto take = [&](size_t bytes) -> void* {
    void* p = ws + off;
    off = (off + bytes + 255) & ~(size_t)255;
    return p;
  };
  __hip_bfloat16* h0b   = (__hip_bfloat16*)take((size_t)64 * 512 * 2);
  float*          c0    = (float*)take((size_t)64 * 512 * 4);
  __hip_bfloat16* xcatb = (__hip_bfloat16*)take((size_t)TBROWS * 96 * 2);
  __hip_bfloat16* hs1   = (__hip_bfloat16*)take((size_t)TBROWS * 512 * 2);
  __hip_bfloat16* hs2   = (__hip_bfloat16*)take((size_t)TBROWS * 512 * 2);
  __hip_bfloat16* hs3   = (__hip_bfloat16*)take((size_t)TBROWS * 512 * 2);
  static const int Kp_[4] = {96, 608, 1024, 1024};
  static const int Ks_[4] = {80, 592, 1024, 1024};
  __hip_bfloat16* wihp[4]; __hip_bfloat16* whhb[4]; float* bsum[4];
  for (int l = 0; l < 4; ++l) {
    wihp[l] = (__hip_bfloat16*)take((size_t)2048 * Kp_[l] * 2);
    whhb[l] = (__hip_bfloat16*)take((size_t)2048 * 512 * 2);
    bsum[l] = (float*)take(2048 * 4);
  }
  unsigned* flags = (unsigned*)take(4 * 128 * 64);

  hipMemsetAsync(flags, 0, 4 * 128 * 64, stream);
  arm_mlp_kernel<<<64, 512, 0, stream>>>(stat, Wh1, bh1, Wh2, bh2, Wh3, bh3,
                                         Wc1, bc1, Wc2, bc2, Wc3, bc3, h0b, c0);
  arm_xcat_kernel<<<1024, 256, 0, stream>>>(stat, rec, xcatb);
  for (int l = 0; l < 4; ++l) {
    arm_cvtpad_kernel<<<512, 256, 0, stream>>>(Wih[l], wihp[l], 2048, Ks_[l], Kp_[l]);
    arm_cvtpad_kernel<<<512, 256, 0, stream>>>(Whh[l], whhb[l], 2048, 512, 512);
    arm_bsum_kernel<<<8, 256, 0, stream>>>(bih[l], bhh[l], bsum[l], 2048);
  }
  float* dbase = out + (size_t)64 * 512 * 16;
  // LSTM1: x(96)            LSTM2: [h1(512), x(96)]
  // LSTM3: [h1(512),h2(512)] LSTM4: [h2(512),h3(512)] ; h4 reuses hs1 buffer
  arm_scan_kernel<<<128, 256, 0, stream>>>(xcatb, 96, 96, (const __hip_bfloat16*)nullptr, 0, 96,
      wihp[0], whhb[0], bsum[0], h0b, c0, hs1, flags + 0 * 128 * 16,
      dbase + 0, dbase + 32768);
  arm_scan_kernel<<<128, 256, 0, stream>>>(hs1, 512, 512, xcatb, 96, 608,
      wihp[1], whhb[1], bsum[1], h0b, c0, hs2, flags + 1 * 128 * 16,
      dbase + 65536, dbase + 98304);
  arm_scan_kernel<<<128, 256, 0, stream>>>(hs1, 512, 512, hs2, 512, 1024,
      wihp[2], whhb[2], bsum[2], h0b, c0, hs3, flags + 2 * 128 * 16,
      dbase + 131072, dbase + 163840);
  arm_scan_kernel<<<128, 256, 0, stream>>>(hs2, 512, 512, hs3, 512, 1024,
      wihp[3], whhb[3], bsum[3], h0b, c0, hs1, flags + 3 * 128 * 16,
      dbase + 196608, dbase + 229376);
  arm_out_kernel<<<2048, 256, 0, stream>>>(hs3, hs1, Wout, bout, out);
}

// Round 3
// 15675.105 us; speedup vs baseline: 2.8253x; 2.8253x over previous
//
#include <hip/hip_runtime.h>
#include <hip/hip_bf16.h>

using short8 = __attribute__((ext_vector_type(8))) short;
using f32x4  = __attribute__((ext_vector_type(4))) float;

#define DEVI __device__ __forceinline__

static constexpr int TBROWS = 64 * 512;   // B*T rows, TB-major: row = t*64 + b
#define WSTR 1544                          // 1536 + 8 bf16 pad (LDS weight row stride)

DEVI float sigm_f(float x) { return 1.f / (1.f + __expf(-x)); }
DEVI float selu_f(float x) {
  return 1.0507009873554805f * (x > 0.f ? x : 1.6732632423543772f * (__expf(x) - 1.f));
}

// ---------------- MLP init: h0 (bf16) and c0 (f32), shared by all 4 LSTMs ----
__global__ __launch_bounds__(512) void arm_mlp_kernel(
    const float* __restrict__ stat,
    const float* __restrict__ Wh1, const float* __restrict__ bh1,
    const float* __restrict__ Wh2, const float* __restrict__ bh2,
    const float* __restrict__ Wh3, const float* __restrict__ bh3,
    const float* __restrict__ Wc1, const float* __restrict__ bc1,
    const float* __restrict__ Wc2, const float* __restrict__ bc2,
    const float* __restrict__ Wc3, const float* __restrict__ bc3,
    __hip_bfloat16* __restrict__ h0b, float* __restrict__ c0)
{
  __shared__ float xs[64], y1[32], y2[32];
  const int b = blockIdx.x, tid = threadIdx.x;
  if (tid < 64) xs[tid] = stat[b * 64 + tid];
  __syncthreads();
  for (int sel = 0; sel < 2; ++sel) {
    const float* W1 = sel ? Wc1 : Wh1; const float* B1 = sel ? bc1 : bh1;
    const float* W2 = sel ? Wc2 : Wh2; const float* B2 = sel ? bc2 : bh2;
    const float* W3 = sel ? Wc3 : Wh3; const float* B3 = sel ? bc3 : bh3;
    if (tid < 32) {
      float a = B1[tid];
      for (int k = 0; k < 64; ++k) a += W1[tid * 64 + k] * xs[k];
      y1[tid] = selu_f(a);
    }
    __syncthreads();
    if (tid < 32) {
      float a = B2[tid];
      for (int k = 0; k < 32; ++k) a += W2[tid * 32 + k] * y1[k];
      y2[tid] = selu_f(a);
    }
    __syncthreads();
    {
      float a = B3[tid];
      for (int k = 0; k < 32; ++k) a += W3[tid * 32 + k] * y2[k];
      a = selu_f(a);
      if (sel == 0) h0b[b * 512 + tid] = __float2bfloat16(a);
      else          c0 [b * 512 + tid] = a;
    }
    __syncthreads();
  }
}

// ---------------- Xcat: [TB][96] bf16, cols 0..63 static, 64..79 rec, 80..95 zero
__global__ __launch_bounds__(256) void arm_xcat_kernel(
    const float* __restrict__ stat, const float* __restrict__ rec,
    __hip_bfloat16* __restrict__ xc)
{
  const int total = TBROWS * 96;
  for (int i = blockIdx.x * 256 + threadIdx.x; i < total; i += gridDim.x * 256) {
    int row = i / 96, k = i - row * 96;
    int t = row >> 6, b = row & 63;
    float v = 0.f;
    if (k < 64)      v = stat[b * 64 + k];
    else if (k < 80) v = rec[((size_t)b * 512 + t) * 16 + (k - 64)];
    xc[i] = __float2bfloat16(v);
  }
}

// ---------------- f32 -> bf16 convert with K padding: dst [N][Kp]
__global__ __launch_bounds__(256) void arm_cvtpad_kernel(
    const float* __restrict__ src, __hip_bfloat16* __restrict__ dst,
    int N, int Ks, int Kp)
{
  const int total = N * Kp;
  for (int i = blockIdx.x * 256 + threadIdx.x; i < total; i += gridDim.x * 256) {
    int n = i / Kp, k = i - n * Kp;
    dst[i] = __float2bfloat16(k < Ks ? src[(size_t)n * Ks + k] : 0.f);
  }
}

__global__ __launch_bounds__(256) void arm_bsum_kernel(
    const float* __restrict__ a, const float* __restrict__ b,
    float* __restrict__ d, int n)
{
  int i = blockIdx.x * 256 + threadIdx.x;
  if (i < n) d[i] = a[i] + b[i];
}

// ---------------- fused 4-layer pipelined LSTM scan ----------------
// 256 persistent blocks. xcd = blk&7, layer l = xcd>>1 (layer -> XCD pair for
// L2 A-panel reuse), n = ((blk>>3)<<1)|(xcd&1) in [0,64): block owns 8 hidden
// units (32 gate rows) x ALL 64 batch rows. Layer l computes t = s - l at
// global step s (wavefront pipeline: all deps produced at step <= s-1).
// 515 global steps, one flag barrier each.

struct FusedParams {
  const __hip_bfloat16* seg1[4];
  const __hip_bfloat16* seg2[4];
  const __hip_bfloat16* wihp[4];
  const __hip_bfloat16* whhb[4];
  const float* bsum[4];
  const __hip_bfloat16* h0b;
  const float* c0;
  __hip_bfloat16* hout[4];
  float* dh[4];
  float* dc[4];
  unsigned* flags;
};

DEVI void post_and_wait(unsigned* __restrict__ fl, int blk, int s, int tid,
                        unsigned& budget)
{
  __syncthreads();                 // all h-stores issued & drained (waitcnt before barrier)
  if (tid == 0) {
    __threadfence();               // release (cheap: h-stores were write-through sc0sc1)
    __hip_atomic_store(fl + blk * 16, (unsigned)(s + 1),
                       __ATOMIC_RELEASE, __HIP_MEMORY_SCOPE_AGENT);
  }
  if (tid < 64) {
    const unsigned tgt = (unsigned)(s + 1);
    while (budget) {
      unsigned v0 = __hip_atomic_load(fl + tid * 16,         __ATOMIC_RELAXED, __HIP_MEMORY_SCOPE_AGENT);
      unsigned v1 = __hip_atomic_load(fl + (64 + tid) * 16,  __ATOMIC_RELAXED, __HIP_MEMORY_SCOPE_AGENT);
      unsigned v2 = __hip_atomic_load(fl + (128 + tid) * 16, __ATOMIC_RELAXED, __HIP_MEMORY_SCOPE_AGENT);
      unsigned v3 = __hip_atomic_load(fl + (192 + tid) * 16, __ATOMIC_RELAXED, __HIP_MEMORY_SCOPE_AGENT);
      unsigned mn = min(min(v0, v1), min(v2, v3));
      if (__all(mn >= tgt)) break;
      --budget;
    }
  }
  __syncthreads();
  __threadfence();                 // acquire: kill stale/prefetched L1/L2 lines
}

template<int KS1, int LDA1, int KS2, int LDA2>
DEVI void run_layer(const __hip_bfloat16* __restrict__ seg1,
                    const __hip_bfloat16* __restrict__ seg2,
                    const __hip_bfloat16* __restrict__ wihp,
                    const __hip_bfloat16* __restrict__ whhb,
                    const float* __restrict__ bsumP,
                    const __hip_bfloat16* __restrict__ h0b,
                    const float* __restrict__ c0,
                    __hip_bfloat16* __restrict__ hseq,
                    float* __restrict__ dh, float* __restrict__ dc,
                    unsigned* __restrict__ fl,
                    int blk, int u0, int skew,
                    __hip_bfloat16* __restrict__ wsl,
                    float (*__restrict__ gbuf)[33],
                    float (*__restrict__ cst)[9],
                    float* __restrict__ bs)
{
  constexpr int KP   = KS1 + KS2;      // padded Wih width
  constexpr int KTOT = KP + 512;
  constexpr int NKS  = KTOT / 32;
  constexpr int CH   = 8;
  constexpr int NCH  = (NKS + CH - 1) / CH;
  constexpr int CPR  = KTOT / 8;       // short8 chunks per LDS weight row

  const int tid = threadIdx.x;

  // stage [Wih | Whh] rows: local gate row c -> global row (c>>3)*512 + u0 + (c&7)
  for (int i = tid; i < 32 * CPR; i += 256) {
    int c = i / CPR, j = i - c * CPR;
    int kk = j << 3;
    int grow = ((c >> 3) << 9) + u0 + (c & 7);
    short8 v;
    if (kk < KP) v = *(const short8*)(wihp + (size_t)grow * KP + kk);
    else         v = *(const short8*)(whhb + ((size_t)grow << 9) + (kk - KP));
    *(short8*)(wsl + c * WSTR + kk) = v;
  }
  if (tid < 32) bs[tid] = bsumP[((tid >> 3) << 9) + u0 + (tid & 7)];
  for (int idx = tid; idx < 512; idx += 256)
    cst[idx >> 3][idx & 7] = c0[(size_t)(idx >> 3) * 512 + u0 + (idx & 7)];
  __syncthreads();

  const int lane = tid & 63, w = tid >> 6;
  const int frow = lane & 15, fk8 = (lane >> 4) << 3;
  const int m = (w << 4) + frow;                 // batch row of this lane's A fragment
  const __hip_bfloat16* wb0 = wsl + frow * WSTR + fk8;          // N-tile 0
  const __hip_bfloat16* wb1 = wsl + (16 + frow) * WSTR + fk8;   // N-tile 1
  unsigned budget = 1u << 24;

  for (int s = 0; s < 515; ++s) {
    const int t = s - skew;
    if (t >= 0 && t <= 511) {
      const size_t rowx = (size_t)(t * 64 + m);
      const __hip_bfloat16* b1p = seg1 + rowx * LDA1 + fk8;
      const __hip_bfloat16* b2p = (KS2 > 0) ? (seg2 + rowx * LDA2 + fk8) : seg1;
      const __hip_bfloat16* bhp = t ? (hseq + (((size_t)(t - 1) * 64 + m) << 9) + fk8)
                                    : (h0b + ((size_t)m << 9) + fk8);
      auto lda_fn = [&](int kk) -> short8 {
        if (kk < KS1)            return *(const short8*)(b1p + kk);
        else if (kk < KS1 + KS2) return *(const short8*)(b2p + (kk - KS1));
        else                     return *(const short8*)(bhp + (kk - KS1 - KS2));
      };

      f32x4 acc0 = {0.f, 0.f, 0.f, 0.f}, acc1 = {0.f, 0.f, 0.f, 0.f};
      short8 acur[CH], anxt[CH];
#pragma unroll
      for (int j = 0; j < CH; ++j) if (j < NKS) acur[j] = lda_fn(j * 32);
#pragma unroll
      for (int c = 0; c < NCH; ++c) {
#pragma unroll
        for (int j = 0; j < CH; ++j) {
          int nn = (c + 1) * CH + j;
          if (nn < NKS) anxt[j] = lda_fn(nn * 32);
        }
#pragma unroll
        for (int j = 0; j < CH; ++j) {
          int ki = c * CH + j;
          if (ki < NKS) {
            const int kk = ki * 32;
            short8 b0 = *(const short8*)(wb0 + kk);
            short8 b1 = *(const short8*)(wb1 + kk);
            acc0 = __builtin_amdgcn_mfma_f32_16x16x32_bf16(acur[j], b0, acc0, 0, 0, 0);
            acc1 = __builtin_amdgcn_mfma_f32_16x16x32_bf16(acur[j], b1, acc1, 0, 0, 0);
          }
        }
#pragma unroll
        for (int j = 0; j < CH; ++j) acur[j] = anxt[j];
      }

      // epilogue: C col = lane&15 (+16 for tile 1), row = w*16 + (lane>>4)*4 + j
      {
        const int crow = (w << 4) + ((lane >> 4) << 2);
#pragma unroll
        for (int j = 0; j < 4; ++j) {
          gbuf[crow + j][frow]      = acc0[j] + bs[frow];
          gbuf[crow + j][16 + frow] = acc1[j] + bs[16 + frow];
        }
      }
      __syncthreads();
      // elementwise: thread -> (batch row bb, unit pair u2,u2+1); gates i,f,g,o
      {
        const int bb = tid >> 2, u2 = (tid & 3) << 1;
        unsigned packed = 0;
        float dhv[2], dcv[2];
#pragma unroll
        for (int q = 0; q < 2; ++q) {
          const int u = u2 + q;
          float gi = gbuf[bb][u],      gf = gbuf[bb][8 + u];
          float gg = gbuf[bb][16 + u], go = gbuf[bb][24 + u];
          float cn = sigm_f(gf) * cst[bb][u] + sigm_f(gi) * tanhf(gg);
          float hn = sigm_f(go) * tanhf(cn);
          cst[bb][u] = cn;
          __hip_bfloat16 hb = __float2bfloat16(hn);
          packed |= ((unsigned)*(unsigned short*)&hb) << (16 * q);
          dhv[q] = hn; dcv[q] = cn;
        }
        // device-coherent (sc0sc1) write-through: visible at L3, no dirty L2
        __hip_atomic_store((unsigned*)(hseq + (((size_t)(t * 64 + bb)) << 9) + u0 + u2),
                           packed, __ATOMIC_RELAXED, __HIP_MEMORY_SCOPE_AGENT);
        if (t == 511) {
          dh[(size_t)bb * 512 + u0 + u2]     = dhv[0];
          dh[(size_t)bb * 512 + u0 + u2 + 1] = dhv[1];
          dc[(size_t)bb * 512 + u0 + u2]     = dcv[0];
          dc[(size_t)bb * 512 + u0 + u2 + 1] = dcv[1];
        }
      }
    }
    post_and_wait(fl, blk, s, tid, budget);
  }
}

__global__ __launch_bounds__(256, 1) void arm_fused_kernel(FusedParams p)
{
  __shared__ __align__(16) __hip_bfloat16 wsl[32 * WSTR];   // 96.5 KB
  __shared__ float gbuf[64][33];                            // 8.4 KB
  __shared__ float cst[64][9];                              // 2.25 KB
  __shared__ float bs[32];

  const int blk = blockIdx.x;
  const int xcd = blk & 7;
  const int l   = xcd >> 1;
  const int n   = ((blk >> 3) << 1) | (xcd & 1);
  const int u0  = n << 3;

  switch (l) {
    case 0: run_layer< 96, 96,   0,   0>(p.seg1[0], p.seg2[0], p.wihp[0], p.whhb[0],
              p.bsum[0], p.h0b, p.c0, p.hout[0], p.dh[0], p.dc[0], p.flags,
              blk, u0, 0, wsl, gbuf, cst, bs); break;
    case 1: run_layer<512, 512, 96,  96>(p.seg1[1], p.seg2[1], p.wihp[1], p.whhb[1],
              p.bsum[1], p.h0b, p.c0, p.hout[1], p.dh[1], p.dc[1], p.flags,
              blk, u0, 1, wsl, gbuf, cst, bs); break;
    case 2: run_layer<512, 512, 512, 512>(p.seg1[2], p.seg2[2], p.wihp[2], p.whhb[2],
              p.bsum[2], p.h0b, p.c0, p.hout[2], p.dh[2], p.dc[2], p.flags,
              blk, u0, 2, wsl, gbuf, cst, bs); break;
    default: run_layer<512, 512, 512, 512>(p.seg1[3], p.seg2[3], p.wihp[3], p.whhb[3],
              p.bsum[3], p.h0b, p.c0, p.hout[3], p.dh[3], p.dc[3], p.flags,
              blk, u0, 3, wsl, gbuf, cst, bs); break;
  }
}

// ---------------- final projection: out = [h3,h4] @ Wout^T + bout, sigmoid(:2)
__global__ __launch_bounds__(256) void arm_out_kernel(
    const __hip_bfloat16* __restrict__ h3b, const __hip_bfloat16* __restrict__ h4b,
    const float* __restrict__ Wout, const float* __restrict__ bout,
    float* __restrict__ out)
{
  __shared__ float w_s[16][1025];
  __shared__ __hip_bfloat16 a_s[16][1032];
  __shared__ float bo[16];
  const int tid = threadIdx.x;
  for (int i = tid; i < 16 * 1024; i += 256) {
    int n = i >> 10, k = i & 1023;
    w_s[n][k] = Wout[i];
  }
  if (tid < 16) bo[tid] = bout[tid];
  const int rb = blockIdx.x * 16;
  for (int i = tid; i < 16 * 512; i += 256) {
    int r = i >> 9, k = i & 511;
    a_s[r][k]       = h3b[(((size_t)(rb + r)) << 9) + k];
    a_s[r][512 + k] = h4b[(((size_t)(rb + r)) << 9) + k];
  }
  __syncthreads();
  const int r = tid >> 4, n = tid & 15;
  float acc = bo[n];
  for (int k = 0; k < 1024; ++k)
    acc += __bfloat162float(a_s[r][k]) * w_s[n][k];
  const int ri = rb + r, t = ri >> 6, b = ri & 63;
  if (n < 2) acc = sigm_f(acc);
  out[((size_t)(b * 512 + t)) * 16 + n] = acc;
}

extern "C" void kernel_launch(void* const* d_in, const int* in_sizes, int n_in,
                              void* d_out, int out_size, void* d_ws, size_t ws_size,
                              hipStream_t stream) {
  (void)in_sizes; (void)n_in; (void)out_size; (void)ws_size;
  const float* stat = (const float*)d_in[0];
  const float* rec  = (const float*)d_in[1];
  const float* Wh1 = (const float*)d_in[2];  const float* bh1 = (const float*)d_in[3];
  const float* Wh2 = (const float*)d_in[4];  const float* bh2 = (const float*)d_in[5];
  const float* Wh3 = (const float*)d_in[6];  const float* bh3 = (const float*)d_in[7];
  const float* Wc1 = (const float*)d_in[8];  const float* bc1 = (const float*)d_in[9];
  const float* Wc2 = (const float*)d_in[10]; const float* bc2 = (const float*)d_in[11];
  const float* Wc3 = (const float*)d_in[12]; const float* bc3 = (const float*)d_in[13];
  const float* Wih[4] = {(const float*)d_in[14], (const float*)d_in[18],
                         (const float*)d_in[22], (const float*)d_in[26]};
  const float* Whh[4] = {(const float*)d_in[15], (const float*)d_in[19],
                         (const float*)d_in[23], (const float*)d_in[27]};
  const float* bih[4] = {(const float*)d_in[16], (const float*)d_in[20],
                         (const float*)d_in[24], (const float*)d_in[28]};
  const float* bhh[4] = {(const float*)d_in[17], (const float*)d_in[21],
                         (const float*)d_in[25], (const float*)d_in[29]};
  const float* Wout = (const float*)d_in[30];
  const float* bout = (const float*)d_in[31];
  float* out = (float*)d_out;

  char* ws = (char*)d_ws;
  size_t off = 0;
  auto take = [&](size_t bytes) -> void* {
    void* p = ws + off;
    off = (off + bytes + 255) & ~(size_t)255;
    return p;
  };
  __hip_bfloat16* h0b   = (__hip_bfloat16*)take((size_t)64 * 512 * 2);
  float*          c0    = (float*)take((size_t)64 * 512 * 4);
  __hip_bfloat16* xcatb = (__hip_bfloat16*)take((size_t)TBROWS * 96 * 2);
  __hip_bfloat16* hs1   = (__hip_bfloat16*)take((size_t)TBROWS * 512 * 2);
  __hip_bfloat16* hs2   = (__hip_bfloat16*)take((size_t)TBROWS * 512 * 2);
  __hip_bfloat16* hs3   = (__hip_bfloat16*)take((size_t)TBROWS * 512 * 2);
  static const int Kp_[4] = {96, 608, 1024, 1024};
  static const int Ks_[4] = {80, 592, 1024, 1024};
  __hip_bfloat16* wihp[4]; __hip_bfloat16* whhb[4]; float* bsum[4];
  for (int l = 0; l < 4; ++l) {
    wihp[l] = (__hip_bfloat16*)take((size_t)2048 * Kp_[l] * 2);
    whhb[l] = (__hip_bfloat16*)take((size_t)2048 * 512 * 2);
    bsum[l] = (float*)take(2048 * 4);
  }
  unsigned* flags = (unsigned*)take(256 * 64);

  hipMemsetAsync(flags, 0, 256 * 64, stream);
  arm_mlp_kernel<<<64, 512, 0, stream>>>(stat, Wh1, bh1, Wh2, bh2, Wh3, bh3,
                                         Wc1, bc1, Wc2, bc2, Wc3, bc3, h0b, c0);
  arm_xcat_kernel<<<1024, 256, 0, stream>>>(stat, rec, xcatb);
  for (int l = 0; l < 4; ++l) {
    arm_cvtpad_kernel<<<512, 256, 0, stream>>>(Wih[l], wihp[l], 2048, Ks_[l], Kp_[l]);
    arm_cvtpad_kernel<<<512, 256, 0, stream>>>(Whh[l], whhb[l], 2048, 512, 512);
    arm_bsum_kernel<<<8, 256, 0, stream>>>(bih[l], bhh[l], bsum[l], 2048);
  }

  float* dbase = out + (size_t)64 * 512 * 16;
  FusedParams p;
  // L1: x(96) -> hs1          L2: [h1(512), x(96)] -> hs2
  // L3: [h1,h2] -> hs3        L4: [h2,h3] -> hs1 (distinct rows per step; safe)
  p.seg1[0] = xcatb; p.seg2[0] = nullptr;
  p.seg1[1] = hs1;   p.seg2[1] = xcatb;
  p.seg1[2] = hs1;   p.seg2[2] = hs2;
  p.seg1[3] = hs2;   p.seg2[3] = hs3;
  for (int l = 0; l < 4; ++l) { p.wihp[l] = wihp[l]; p.whhb[l] = whhb[l]; p.bsum[l] = bsum[l]; }
  p.h0b = h0b; p.c0 = c0;
  p.hout[0] = hs1; p.hout[1] = hs2; p.hout[2] = hs3; p.hout[3] = hs1;
  for (int l = 0; l < 4; ++l) {
    p.dh[l] = dbase + l * 65536;
    p.dc[l] = dbase + l * 65536 + 32768;
  }
  p.flags = flags;

  arm_fused_kernel<<<256, 256, 0, stream>>>(p);
  arm_out_kernel<<<2048, 256, 0, stream>>>(hs3, hs1, Wout, bout, out);
}

// Round 4
// 10906.030 us; speedup vs baseline: 4.0608x; 1.4373x over previous
//
#include <hip/hip_runtime.h>
#include <hip/hip_bf16.h>

using short8 = __attribute__((ext_vector_type(8))) short;
using f32x4  = __attribute__((ext_vector_type(4))) float;

#define DEVI __device__ __forceinline__

static constexpr int TBROWS = 64 * 512;   // B*T rows, TB-major: row = t*64 + b
#define WSTR 1544                          // 1536 + 8 bf16 pad (LDS weight row stride)

DEVI float sigm_f(float x) { return 1.f / (1.f + __expf(-x)); }
DEVI float selu_f(float x) {
  return 1.0507009873554805f * (x > 0.f ? x : 1.6732632423543772f * (__expf(x) - 1.f));
}

// ---------------- MLP init: h0 (bf16) and c0 (f32), shared by all 4 LSTMs ----
__global__ __launch_bounds__(512) void arm_mlp_kernel(
    const float* __restrict__ stat,
    const float* __restrict__ Wh1, const float* __restrict__ bh1,
    const float* __restrict__ Wh2, const float* __restrict__ bh2,
    const float* __restrict__ Wh3, const float* __restrict__ bh3,
    const float* __restrict__ Wc1, const float* __restrict__ bc1,
    const float* __restrict__ Wc2, const float* __restrict__ bc2,
    const float* __restrict__ Wc3, const float* __restrict__ bc3,
    __hip_bfloat16* __restrict__ h0b, float* __restrict__ c0)
{
  __shared__ float xs[64], y1[32], y2[32];
  const int b = blockIdx.x, tid = threadIdx.x;
  if (tid < 64) xs[tid] = stat[b * 64 + tid];
  __syncthreads();
  for (int sel = 0; sel < 2; ++sel) {
    const float* W1 = sel ? Wc1 : Wh1; const float* B1 = sel ? bc1 : bh1;
    const float* W2 = sel ? Wc2 : Wh2; const float* B2 = sel ? bc2 : bh2;
    const float* W3 = sel ? Wc3 : Wh3; const float* B3 = sel ? bc3 : bh3;
    if (tid < 32) {
      float a = B1[tid];
      for (int k = 0; k < 64; ++k) a += W1[tid * 64 + k] * xs[k];
      y1[tid] = selu_f(a);
    }
    __syncthreads();
    if (tid < 32) {
      float a = B2[tid];
      for (int k = 0; k < 32; ++k) a += W2[tid * 32 + k] * y1[k];
      y2[tid] = selu_f(a);
    }
    __syncthreads();
    {
      float a = B3[tid];
      for (int k = 0; k < 32; ++k) a += W3[tid * 32 + k] * y2[k];
      a = selu_f(a);
      if (sel == 0) h0b[b * 512 + tid] = __float2bfloat16(a);
      else          c0 [b * 512 + tid] = a;
    }
    __syncthreads();
  }
}

// ---------------- Xcat: [TB][96] bf16, cols 0..63 static, 64..79 rec, 80..95 zero
__global__ __launch_bounds__(256) void arm_xcat_kernel(
    const float* __restrict__ stat, const float* __restrict__ rec,
    __hip_bfloat16* __restrict__ xc)
{
  const int total = TBROWS * 96;
  for (int i = blockIdx.x * 256 + threadIdx.x; i < total; i += gridDim.x * 256) {
    int row = i / 96, k = i - row * 96;
    int t = row >> 6, b = row & 63;
    float v = 0.f;
    if (k < 64)      v = stat[b * 64 + k];
    else if (k < 80) v = rec[((size_t)b * 512 + t) * 16 + (k - 64)];
    xc[i] = __float2bfloat16(v);
  }
}

// ---------------- f32 -> bf16 convert with K padding: dst [N][Kp]
__global__ __launch_bounds__(256) void arm_cvtpad_kernel(
    const float* __restrict__ src, __hip_bfloat16* __restrict__ dst,
    int N, int Ks, int Kp)
{
  const int total = N * Kp;
  for (int i = blockIdx.x * 256 + threadIdx.x; i < total; i += gridDim.x * 256) {
    int n = i / Kp, k = i - n * Kp;
    dst[i] = __float2bfloat16(k < Ks ? src[(size_t)n * Ks + k] : 0.f);
  }
}

__global__ __launch_bounds__(256) void arm_bsum_kernel(
    const float* __restrict__ a, const float* __restrict__ b,
    float* __restrict__ d, int n)
{
  int i = blockIdx.x * 256 + threadIdx.x;
  if (i < n) d[i] = a[i] + b[i];
}

// ---------------- fused 4-layer dataflow-pipelined LSTM scan ----------------
// 256 persistent blocks. xcd = blk&7, layer L = xcd>>1, n = ((blk>>3)<<1)|(xcd&1)
// in [0,64): block owns 8 hidden units (32 gate rows) x ALL 64 batch rows.
// No global barrier: per-layer arrival counter cnt[L] (release atomicAdd;
// 64th arrival for step t posts done[L]=t+1). Consumers poll only their dep
// flags (4 cachelines device-wide), then one agent-acquire fence (buffer_inv).
// h stored with PLAIN stores; the release atomicAdd's buffer_wbl2 flushes them
// to L3 (write-back allocate) so readers hit L3, not HBM.
//
// Dep conditions at local step t (done[l] = # completed steps of layer l):
//   L0: done0>=t                       (own h(t-1); x is static)
//   L1: done0>=t+1, done1>=t
//   L2: done0>=t+1, done1>=t+1, done2>=t
//   L3: done1>=t+1, done2>=t+1, done3>=t
// L3 writes h4 into hs1 (h1's buffer) row t: safe, since done1/done2>=t+1
// guarantee L1's consumers finished reading hs1 rows <= t.

struct FusedParams {
  const __hip_bfloat16* seg1[4];
  const __hip_bfloat16* seg2[4];
  const __hip_bfloat16* wihp[4];
  const __hip_bfloat16* whhb[4];
  const float* bsum[4];
  const __hip_bfloat16* h0b;
  const float* c0;
  __hip_bfloat16* hout[4];
  float* dh[4];
  float* dc[4];
  unsigned* sync;    // cnt[l] at l*16 u32; done[l] at 64 + l*16 u32
};

DEVI void wave_wait(const unsigned* __restrict__ dn,
                    int n0, int n1, int n2, int n3, unsigned& budget)
{
  const int d = threadIdx.x & 3;
  const int need = (d == 0) ? n0 : (d == 1) ? n1 : (d == 2) ? n2 : n3;
  if (need > 0) {                       // lanes with need<=0 drop out of __all
    while (budget) {
      unsigned v = __hip_atomic_load(dn + d * 16, __ATOMIC_RELAXED,
                                     __HIP_MEMORY_SCOPE_AGENT);
      if (__all((int)v >= need)) break;
      --budget;
    }
  }
}

template<int KS1, int LDA1, int KS2, int LDA2, int L>
DEVI void run_layer(const __hip_bfloat16* __restrict__ seg1,
                    const __hip_bfloat16* __restrict__ seg2,
                    const __hip_bfloat16* __restrict__ wihp,
                    const __hip_bfloat16* __restrict__ whhb,
                    const float* __restrict__ bsumP,
                    const __hip_bfloat16* __restrict__ h0b,
                    const float* __restrict__ c0,
                    __hip_bfloat16* __restrict__ hseq,
                    float* __restrict__ dh, float* __restrict__ dc,
                    unsigned* __restrict__ syncp,
                    int u0,
                    __hip_bfloat16* __restrict__ wsl,
                    float (*__restrict__ gbuf)[33],
                    float (*__restrict__ cst)[9],
                    float* __restrict__ bs)
{
  constexpr int KP   = KS1 + KS2;      // padded Wih width
  constexpr int KTOT = KP + 512;
  constexpr int NKS  = KTOT / 32;      // 32-wide K chunks
  constexpr int NR   = (NKS + 15) / 16;
  constexpr int CPR  = KTOT / 8;       // short8 chunks per LDS weight row

  const int tid = threadIdx.x;
  unsigned* cnt = syncp + L * 16;
  unsigned* dn  = syncp + 64;

  // stage [Wih | Whh] rows: local gate row c -> global row (c>>3)*512 + u0 + (c&7)
  for (int i = tid; i < 32 * CPR; i += 256) {
    int c = i / CPR, j = i - c * CPR;
    int kk = j << 3;
    int grow = ((c >> 3) << 9) + u0 + (c & 7);
    short8 v;
    if (kk < KP) v = *(const short8*)(wihp + (size_t)grow * KP + kk);
    else         v = *(const short8*)(whhb + ((size_t)grow << 9) + (kk - KP));
    *(short8*)(wsl + c * WSTR + kk) = v;
  }
  if (tid < 32) bs[tid] = bsumP[((tid >> 3) << 9) + u0 + (tid & 7)];
  for (int idx = tid; idx < 512; idx += 256)
    cst[idx >> 3][idx & 7] = c0[(size_t)(idx >> 3) * 512 + u0 + (idx & 7)];
  __syncthreads();

  const int lane = tid & 63, w = tid >> 6;
  const int frow = lane & 15, fk8 = (lane >> 4) << 3;
  const int m = (w << 4) + frow;                 // batch row of this lane's A fragment
  const __hip_bfloat16* wb0 = wsl + frow * WSTR + fk8;          // N-tile 0
  const __hip_bfloat16* wb1 = wsl + (16 + frow) * WSTR + fk8;   // N-tile 1
  unsigned budget = 1u << 24;

#pragma unroll 1
  for (int t = 0; t < 512; ++t) {
    // ---- dataflow wait (4 flag cachelines device-wide) ----
    int n0, n1, n2, n3;
    if (L == 0)      { n0 = t;     n1 = 0;     n2 = 0;     n3 = 0; }
    else if (L == 1) { n0 = t + 1; n1 = t;     n2 = 0;     n3 = 0; }
    else if (L == 2) { n0 = t + 1; n1 = t + 1; n2 = t;     n3 = 0; }
    else             { n0 = 0;     n1 = t + 1; n2 = t + 1; n3 = t; }
    wave_wait(dn, n0, n1, n2, n3, budget);
    __builtin_amdgcn_fence(__ATOMIC_ACQUIRE, "agent");   // inv L1/L2 -> read fresh h from L3

    // ---- A loads + MFMA, rounds of 16 chunks (deep MLP vs L3 latency) ----
    const size_t rowx = (size_t)(t * 64 + m);
    const __hip_bfloat16* b1p = seg1 + rowx * LDA1 + fk8;
    const __hip_bfloat16* b2p = (KS2 > 0) ? (seg2 + rowx * LDA2 + fk8) : seg1;
    const __hip_bfloat16* bhp = t ? (hseq + (((size_t)(t - 1) * 64 + m) << 9) + fk8)
                                  : (h0b + ((size_t)m << 9) + fk8);
    f32x4 acc0 = {0.f, 0.f, 0.f, 0.f}, acc1 = {0.f, 0.f, 0.f, 0.f};
#pragma unroll
    for (int r = 0; r < NR; ++r) {
      short8 a[16];
#pragma unroll
      for (int j = 0; j < 16; ++j) {
        const int ki = r * 16 + j;
        if (ki < NKS) {
          const int kk = ki * 32;
          if (kk < KS1)            a[j] = *(const short8*)(b1p + kk);
          else if (kk < KS1 + KS2) a[j] = *(const short8*)(b2p + (kk - KS1));
          else                     a[j] = *(const short8*)(bhp + (kk - KP));
        }
      }
#pragma unroll
      for (int j = 0; j < 16; ++j) {
        const int ki = r * 16 + j;
        if (ki < NKS) {
          const int kk = ki * 32;
          short8 b0 = *(const short8*)(wb0 + kk);
          short8 b1 = *(const short8*)(wb1 + kk);
          acc0 = __builtin_amdgcn_mfma_f32_16x16x32_bf16(a[j], b0, acc0, 0, 0, 0);
          acc1 = __builtin_amdgcn_mfma_f32_16x16x32_bf16(a[j], b1, acc1, 0, 0, 0);
        }
      }
    }

    // epilogue: C col = lane&15 (+16 for tile 1), row = w*16 + (lane>>4)*4 + j
    {
      const int crow = (w << 4) + ((lane >> 4) << 2);
#pragma unroll
      for (int j = 0; j < 4; ++j) {
        gbuf[crow + j][frow]      = acc0[j] + bs[frow];
        gbuf[crow + j][16 + frow] = acc1[j] + bs[16 + frow];
      }
    }
    __syncthreads();
    // elementwise: thread -> (batch row bb, unit pair u2,u2+1); gates i,f,g,o
    {
      const int bb = tid >> 2, u2 = (tid & 3) << 1;
      unsigned packed = 0;
      float dhv[2], dcv[2];
#pragma unroll
      for (int q = 0; q < 2; ++q) {
        const int u = u2 + q;
        float gi = gbuf[bb][u],      gf = gbuf[bb][8 + u];
        float gg = gbuf[bb][16 + u], go = gbuf[bb][24 + u];
        float cn = sigm_f(gf) * cst[bb][u] + sigm_f(gi) * tanhf(gg);
        float hn = sigm_f(go) * tanhf(cn);
        cst[bb][u] = cn;
        __hip_bfloat16 hb = __float2bfloat16(hn);
        packed |= ((unsigned)*(unsigned short*)&hb) << (16 * q);
        dhv[q] = hn; dcv[q] = cn;
      }
      // plain store: dirty L2; flushed to L3 by the release atomicAdd's wbl2
      *(unsigned*)(hseq + (((size_t)(t * 64 + bb)) << 9) + u0 + u2) = packed;
      if (t == 511) {
        dh[(size_t)bb * 512 + u0 + u2]     = dhv[0];
        dh[(size_t)bb * 512 + u0 + u2 + 1] = dhv[1];
        dc[(size_t)bb * 512 + u0 + u2]     = dcv[0];
        dc[(size_t)bb * 512 + u0 + u2 + 1] = dcv[1];
      }
    }
    __syncthreads();   // drains all waves' h-stores to L2 before the release RMW
    if (tid == 0) {
      unsigned ret = __hip_atomic_fetch_add(cnt, 1u, __ATOMIC_RELEASE,
                                            __HIP_MEMORY_SCOPE_AGENT);
      if (ret + 1u == 64u * (unsigned)(t + 1))
        __hip_atomic_store(dn + L * 16, (unsigned)(t + 1),
                           __ATOMIC_RELEASE, __HIP_MEMORY_SCOPE_AGENT);
    }
  }
}

__global__ __launch_bounds__(256, 1) void arm_fused_kernel(FusedParams p)
{
  __shared__ __align__(16) __hip_bfloat16 wsl[32 * WSTR];   // 96.5 KB
  __shared__ float gbuf[64][33];                            // 8.4 KB
  __shared__ float cst[64][9];                              // 2.25 KB
  __shared__ float bs[32];

  const int blk = blockIdx.x;
  const int xcd = blk & 7;
  const int l   = xcd >> 1;
  const int n   = ((blk >> 3) << 1) | (xcd & 1);
  const int u0  = n << 3;

  switch (l) {
    case 0: run_layer< 96, 96,   0,   0, 0>(p.seg1[0], p.seg2[0], p.wihp[0], p.whhb[0],
              p.bsum[0], p.h0b, p.c0, p.hout[0], p.dh[0], p.dc[0], p.sync,
              u0, wsl, gbuf, cst, bs); break;
    case 1: run_layer<512, 512, 96,  96, 1>(p.seg1[1], p.seg2[1], p.wihp[1], p.whhb[1],
              p.bsum[1], p.h0b, p.c0, p.hout[1], p.dh[1], p.dc[1], p.sync,
              u0, wsl, gbuf, cst, bs); break;
    case 2: run_layer<512, 512, 512, 512, 2>(p.seg1[2], p.seg2[2], p.wihp[2], p.whhb[2],
              p.bsum[2], p.h0b, p.c0, p.hout[2], p.dh[2], p.dc[2], p.sync,
              u0, wsl, gbuf, cst, bs); break;
    default: run_layer<512, 512, 512, 512, 3>(p.seg1[3], p.seg2[3], p.wihp[3], p.whhb[3],
              p.bsum[3], p.h0b, p.c0, p.hout[3], p.dh[3], p.dc[3], p.sync,
              u0, wsl, gbuf, cst, bs); break;
  }
}

// ---------------- final projection: out = [h3,h4] @ Wout^T + bout, sigmoid(:2)
__global__ __launch_bounds__(256) void arm_out_kernel(
    const __hip_bfloat16* __restrict__ h3b, const __hip_bfloat16* __restrict__ h4b,
    const float* __restrict__ Wout, const float* __restrict__ bout,
    float* __restrict__ out)
{
  __shared__ float w_s[16][1025];
  __shared__ __hip_bfloat16 a_s[16][1032];
  __shared__ float bo[16];
  const int tid = threadIdx.x;
  for (int i = tid; i < 16 * 1024; i += 256) {
    int n = i >> 10, k = i & 1023;
    w_s[n][k] = Wout[i];
  }
  if (tid < 16) bo[tid] = bout[tid];
  const int rb = blockIdx.x * 16;
  for (int i = tid; i < 16 * 512; i += 256) {
    int r = i >> 9, k = i & 511;
    a_s[r][k]       = h3b[(((size_t)(rb + r)) << 9) + k];
    a_s[r][512 + k] = h4b[(((size_t)(rb + r)) << 9) + k];
  }
  __syncthreads();
  const int r = tid >> 4, n = tid & 15;
  float acc = bo[n];
  for (int k = 0; k < 1024; ++k)
    acc += __bfloat162float(a_s[r][k]) * w_s[n][k];
  const int ri = rb + r, t = ri >> 6, b = ri & 63;
  if (n < 2) acc = sigm_f(acc);
  out[((size_t)(b * 512 + t)) * 16 + n] = acc;
}

extern "C" void kernel_launch(void* const* d_in, const int* in_sizes, int n_in,
                              void* d_out, int out_size, void* d_ws, size_t ws_size,
                              hipStream_t stream) {
  (void)in_sizes; (void)n_in; (void)out_size; (void)ws_size;
  const float* stat = (const float*)d_in[0];
  const float* rec  = (const float*)d_in[1];
  const float* Wh1 = (const float*)d_in[2];  const float* bh1 = (const float*)d_in[3];
  const float* Wh2 = (const float*)d_in[4];  const float* bh2 = (const float*)d_in[5];
  const float* Wh3 = (const float*)d_in[6];  const float* bh3 = (const float*)d_in[7];
  const float* Wc1 = (const float*)d_in[8];  const float* bc1 = (const float*)d_in[9];
  const float* Wc2 = (const float*)d_in[10]; const float* bc2 = (const float*)d_in[11];
  const float* Wc3 = (const float*)d_in[12]; const float* bc3 = (const float*)d_in[13];
  const float* Wih[4] = {(const float*)d_in[14], (const float*)d_in[18],
                         (const float*)d_in[22], (const float*)d_in[26]};
  const float* Whh[4] = {(const float*)d_in[15], (const float*)d_in[19],
                         (const float*)d_in[23], (const float*)d_in[27]};
  const float* bih[4] = {(const float*)d_in[16], (const float*)d_in[20],
                         (const float*)d_in[24], (const float*)d_in[28]};
  const float* bhh[4] = {(const float*)d_in[17], (const float*)d_in[21],
                         (const float*)d_in[25], (const float*)d_in[29]};
  const float* Wout = (const float*)d_in[30];
  const float* bout = (const float*)d_in[31];
  float* out = (float*)d_out;

  char* ws = (char*)d_ws;
  size_t off = 0;
  auto take = [&](size_t bytes) -> void* {
    void* p = ws + off;
    off = (off + bytes + 255) & ~(size_t)255;
    return p;
  };
  __hip_bfloat16* h0b   = (__hip_bfloat16*)take((size_t)64 * 512 * 2);
  float*          c0    = (float*)take((size_t)64 * 512 * 4);
  __hip_bfloat16* xcatb = (__hip_bfloat16*)take((size_t)TBROWS * 96 * 2);
  __hip_bfloat16* hs1   = (__hip_bfloat16*)take((size_t)TBROWS * 512 * 2);
  __hip_bfloat16* hs2   = (__hip_bfloat16*)take((size_t)TBROWS * 512 * 2);
  __hip_bfloat16* hs3   = (__hip_bfloat16*)take((size_t)TBROWS * 512 * 2);
  static const int Kp_[4] = {96, 608, 1024, 1024};
  static const int Ks_[4] = {80, 592, 1024, 1024};
  __hip_bfloat16* wihp[4]; __hip_bfloat16* whhb[4]; float* bsum[4];
  for (int l = 0; l < 4; ++l) {
    wihp[l] = (__hip_bfloat16*)take((size_t)2048 * Kp_[l] * 2);
    whhb[l] = (__hip_bfloat16*)take((size_t)2048 * 512 * 2);
    bsum[l] = (float*)take(2048 * 4);
  }
  unsigned* syncw = (unsigned*)take(512);

  hipMemsetAsync(syncw, 0, 512, stream);
  arm_mlp_kernel<<<64, 512, 0, stream>>>(stat, Wh1, bh1, Wh2, bh2, Wh3, bh3,
                                         Wc1, bc1, Wc2, bc2, Wc3, bc3, h0b, c0);
  arm_xcat_kernel<<<1024, 256, 0, stream>>>(stat, rec, xcatb);
  for (int l = 0; l < 4; ++l) {
    arm_cvtpad_kernel<<<512, 256, 0, stream>>>(Wih[l], wihp[l], 2048, Ks_[l], Kp_[l]);
    arm_cvtpad_kernel<<<512, 256, 0, stream>>>(Whh[l], whhb[l], 2048, 512, 512);
    arm_bsum_kernel<<<8, 256, 0, stream>>>(bih[l], bhh[l], bsum[l], 2048);
  }

  float* dbase = out + (size_t)64 * 512 * 16;
  FusedParams p;
  // L1: x(96) -> hs1          L2: [h1(512), x(96)] -> hs2
  // L3: [h1,h2] -> hs3        L4: [h2,h3] -> hs1 (WAR-safe via done1/done2 waits)
  p.seg1[0] = xcatb; p.seg2[0] = nullptr;
  p.seg1[1] = hs1;   p.seg2[1] = xcatb;
  p.seg1[2] = hs1;   p.seg2[2] = hs2;
  p.seg1[3] = hs2;   p.seg2[3] = hs3;
  for (int l = 0; l < 4; ++l) { p.wihp[l] = wihp[l]; p.whhb[l] = whhb[l]; p.bsum[l] = bsum[l]; }
  p.h0b = h0b; p.c0 = c0;
  p.hout[0] = hs1; p.hout[1] = hs2; p.hout[2] = hs3; p.hout[3] = hs1;
  for (int l = 0; l < 4; ++l) {
    p.dh[l] = dbase + l * 65536;
    p.dc[l] = dbase + l * 65536 + 32768;
  }
  p.sync = syncw;

  arm_fused_kernel<<<256, 256, 0, stream>>>(p);
  arm_out_kernel<<<2048, 256, 0, stream>>>(hs3, hs1, Wout, bout, out);
}

// Round 6
// 4381.950 us; speedup vs baseline: 10.1067x; 2.4889x over previous
//
#include <hip/hip_runtime.h>
#include <hip/hip_bf16.h>

using short8 = __attribute__((ext_vector_type(8))) short;
using f32x4  = __attribute__((ext_vector_type(4))) float;

#define DEVI __device__ __forceinline__

static constexpr int TBROWS = 64 * 512;   // B*T rows, TB-major: row = t*64 + b
#define WSTR 1544                          // 1536 + 8 bf16 pad (LDS weight row stride)

DEVI float sigm_f(float x) { return 1.f / (1.f + __expf(-x)); }
DEVI float tanh_f(float x) { float e = __expf(2.f * x); return 1.f - 2.f / (e + 1.f); }
DEVI float selu_f(float x) {
  return 1.0507009873554805f * (x > 0.f ? x : 1.6732632423543772f * (__expf(x) - 1.f));
}

// device-coherent (agent) accesses: loads probe through L1/L2 (sc1), stores
// write through to the coherence point (sc0 sc1). No buffer_inv / buffer_wbl2
// anywhere in the hot loop.
DEVI short8 ldg_sc1(const void* p) {
  short8 r;
  asm volatile("global_load_dwordx4 %0, %1, off sc1" : "=v"(r) : "v"(p));
  return r;
}
DEVI short8 ldg_nc(const void* p) {
  short8 r;
  asm volatile("global_load_dwordx4 %0, %1, off" : "=v"(r) : "v"(p));
  return r;
}
DEVI void stg32_cc(void* p, unsigned v) {
  asm volatile("global_store_dword %0, %1, off sc0 sc1" :: "v"(p), "v"(v) : "memory");
}
template<int N> DEVI void waitv() {
  if constexpr (N == 0)       asm volatile("s_waitcnt vmcnt(0)" ::: "memory");
  else if constexpr (N == 3)  asm volatile("s_waitcnt vmcnt(3)" ::: "memory");
  else if constexpr (N == 16) asm volatile("s_waitcnt vmcnt(16)" ::: "memory");
  else static_assert(N == 0 || N == 3 || N == 16, "unsupported vmcnt");
}

// ---------------- MLP init: h0 (bf16) and c0 (f32), shared by all 4 LSTMs ----
__global__ __launch_bounds__(512) void arm_mlp_kernel(
    const float* __restrict__ stat,
    const float* __restrict__ Wh1, const float* __restrict__ bh1,
    const float* __restrict__ Wh2, const float* __restrict__ bh2,
    const float* __restrict__ Wh3, const float* __restrict__ bh3,
    const float* __restrict__ Wc1, const float* __restrict__ bc1,
    const float* __restrict__ Wc2, const float* __restrict__ bc2,
    const float* __restrict__ Wc3, const float* __restrict__ bc3,
    __hip_bfloat16* __restrict__ h0b, float* __restrict__ c0)
{
  __shared__ float xs[64], y1[32], y2[32];
  const int b = blockIdx.x, tid = threadIdx.x;
  if (tid < 64) xs[tid] = stat[b * 64 + tid];
  __syncthreads();
  for (int sel = 0; sel < 2; ++sel) {
    const float* W1 = sel ? Wc1 : Wh1; const float* B1 = sel ? bc1 : bh1;
    const float* W2 = sel ? Wc2 : Wh2; const float* B2 = sel ? bc2 : bh2;
    const float* W3 = sel ? Wc3 : Wh3; const float* B3 = sel ? bc3 : bh3;
    if (tid < 32) {
      float a = B1[tid];
      for (int k = 0; k < 64; ++k) a += W1[tid * 64 + k] * xs[k];
      y1[tid] = selu_f(a);
    }
    __syncthreads();
    if (tid < 32) {
      float a = B2[tid];
      for (int k = 0; k < 32; ++k) a += W2[tid * 32 + k] * y1[k];
      y2[tid] = selu_f(a);
    }
    __syncthreads();
    {
      float a = B3[tid];
      for (int k = 0; k < 32; ++k) a += W3[tid * 32 + k] * y2[k];
      a = selu_f(a);
      if (sel == 0) h0b[b * 512 + tid] = __float2bfloat16(a);
      else          c0 [b * 512 + tid] = a;
    }
    __syncthreads();
  }
}

// ---------------- Xcat: [TB][96] bf16, cols 0..63 static, 64..79 rec, 80..95 zero
__global__ __launch_bounds__(256) void arm_xcat_kernel(
    const float* __restrict__ stat, const float* __restrict__ rec,
    __hip_bfloat16* __restrict__ xc)
{
  const int total = TBROWS * 96;
  for (int i = blockIdx.x * 256 + threadIdx.x; i < total; i += gridDim.x * 256) {
    int row = i / 96, k = i - row * 96;
    int t = row >> 6, b = row & 63;
    float v = 0.f;
    if (k < 64)      v = stat[b * 64 + k];
    else if (k < 80) v = rec[((size_t)b * 512 + t) * 16 + (k - 64)];
    xc[i] = __float2bfloat16(v);
  }
}

// ---------------- f32 -> bf16 convert with K padding: dst [N][Kp]
__global__ __launch_bounds__(256) void arm_cvtpad_kernel(
    const float* __restrict__ src, __hip_bfloat16* __restrict__ dst,
    int N, int Ks, int Kp)
{
  const int total = N * Kp;
  for (int i = blockIdx.x * 256 + threadIdx.x; i < total; i += gridDim.x * 256) {
    int n = i / Kp, k = i - n * Kp;
    dst[i] = __float2bfloat16(k < Ks ? src[(size_t)n * Ks + k] : 0.f);
  }
}

__global__ __launch_bounds__(256) void arm_bsum_kernel(
    const float* __restrict__ a, const float* __restrict__ b,
    float* __restrict__ d, int n)
{
  int i = blockIdx.x * 256 + threadIdx.x;
  if (i < n) d[i] = a[i] + b[i];
}

// ---------------- fused 4-layer dataflow-pipelined LSTM scan ----------------
// 256 persistent blocks. xcd = blk&7, layer L = xcd>>1, n = ((blk>>3)<<1)|(xcd&1)
// in [0,64): block owns 8 hidden units (32 gate rows) x ALL 64 batch rows.
// Sync: per-block flag word flags[(L*64+n)*16] = completed-step count, posted
// with a relaxed agent atomic store after an explicit vmcnt(0) drain of the
// device-coherent h stores. Consumers poll producer-layer flags directly:
// wave 0, lane i checks block i of each dep layer (<=4 sc1 loads per lane per
// poll iteration, all in flight simultaneously). No fences, no wbl2/inv.
//
// Dep needs at local step t (flag = completed steps):
//   L0: own>=t
//   L1: f0>=t+1, own>=t
//   L2: f0>=t+1, f1>=t+1, own>=t
//   L3: f0>=min(t+2,512) [WAR: L0 reads hs1 row t at its step t+1 before L3
//       overwrites it with h4], f1>=t+1, f2>=t+1, own>=t

struct FusedParams {
  const __hip_bfloat16* seg1[4];
  const __hip_bfloat16* seg2[4];
  const __hip_bfloat16* wihp[4];
  const __hip_bfloat16* whhb[4];
  const float* bsum[4];
  const __hip_bfloat16* h0b;
  const float* c0;
  __hip_bfloat16* hout[4];
  float* dh[4];
  float* dc[4];
  unsigned* flags;   // 256 slots, 16 u32 (64 B) apart: [(L*64+n)*16]
};

DEVI unsigned ldf(const unsigned* fl, int D, int i) {
  return __hip_atomic_load(fl + (D * 64 + i) * 16, __ATOMIC_RELAXED,
                           __HIP_MEMORY_SCOPE_AGENT);
}

// issue one round of up to 16 A-chunk loads (x segs cached, h segs sc1)
template<int R, int NKS, int KS1, int KS2, bool S1H, bool S2H>
DEVI void issue_round(short8* ab,
                      const __hip_bfloat16* b1p, const __hip_bfloat16* b2p,
                      const __hip_bfloat16* bhp)
{
#pragma unroll
  for (int j = 0; j < 16; ++j) {
    const int ki = R * 16 + j;
    if (ki < NKS) {
      const int kk = ki * 32;
      if (kk < KS1)             ab[j] = S1H ? ldg_sc1(b1p + kk) : ldg_nc(b1p + kk);
      else if (kk < KS1 + KS2)  ab[j] = S2H ? ldg_sc1(b2p + (kk - KS1)) : ldg_nc(b2p + (kk - KS1));
      else                      ab[j] = ldg_sc1(bhp + (kk - KS1 - KS2));
    }
  }
}

template<int R, int NKS>
DEVI void mfma_round(const short8* ab,
                     const __hip_bfloat16* wb0, const __hip_bfloat16* wb1,
                     f32x4& acc0, f32x4& acc1)
{
#pragma unroll
  for (int j = 0; j < 16; ++j) {
    const int ki = R * 16 + j;
    if (ki < NKS) {
      const int kk = ki * 32;
      short8 b0 = *(const short8*)(wb0 + kk);
      short8 b1 = *(const short8*)(wb1 + kk);
      acc0 = __builtin_amdgcn_mfma_f32_16x16x32_bf16(ab[j], b0, acc0, 0, 0, 0);
      acc1 = __builtin_amdgcn_mfma_f32_16x16x32_bf16(ab[j], b1, acc1, 0, 0, 0);
    }
  }
}

template<int KS1, int LDA1, int KS2, int LDA2, bool S1H, bool S2H, int L>
DEVI void run_layer(const __hip_bfloat16* __restrict__ seg1,
                    const __hip_bfloat16* __restrict__ seg2,
                    const __hip_bfloat16* __restrict__ wihp,
                    const __hip_bfloat16* __restrict__ whhb,
                    const float* __restrict__ bsumP,
                    const __hip_bfloat16* __restrict__ h0b,
                    const float* __restrict__ c0,
                    __hip_bfloat16* __restrict__ hseq,
                    float* __restrict__ dh, float* __restrict__ dc,
                    unsigned* __restrict__ fl,
                    int u0,
                    __hip_bfloat16* __restrict__ wsl,
                    float (*__restrict__ gbuf)[33],
                    float (*__restrict__ cst)[9],
                    float* __restrict__ bs)
{
  constexpr int KP   = KS1 + KS2;
  constexpr int KTOT = KP + 512;
  constexpr int NKS  = KTOT / 32;
  constexpr int NR   = (NKS + 15) / 16;
  constexpr int C1   = (NR > 1) ? ((NKS - 16 < 16) ? NKS - 16 : 16) : 0;
  constexpr int C2   = (NR > 2) ? ((NKS - 32 < 16) ? NKS - 32 : 16) : 0;
  constexpr int CPR  = KTOT / 8;

  const int tid = threadIdx.x;
  const int n   = u0 >> 3;

  // stage [Wih | Whh] rows: local gate row c -> global row (c>>3)*512 + u0 + (c&7)
  for (int i = tid; i < 32 * CPR; i += 256) {
    int c = i / CPR, j = i - c * CPR;
    int kk = j << 3;
    int grow = ((c >> 3) << 9) + u0 + (c & 7);
    short8 v;
    if (kk < KP) v = *(const short8*)(wihp + (size_t)grow * KP + kk);
    else         v = *(const short8*)(whhb + ((size_t)grow << 9) + (kk - KP));
    *(short8*)(wsl + c * WSTR + kk) = v;
  }
  if (tid < 32) bs[tid] = bsumP[((tid >> 3) << 9) + u0 + (tid & 7)];
  for (int idx = tid; idx < 512; idx += 256)
    cst[idx >> 3][idx & 7] = c0[(size_t)(idx >> 3) * 512 + u0 + (idx & 7)];
  __syncthreads();

  const int lane = tid & 63, w = tid >> 6;
  const int frow = lane & 15, fk8 = (lane >> 4) << 3;
  const int m = (w << 4) + frow;                 // batch row of this lane's A fragment
  const __hip_bfloat16* wb0 = wsl + frow * WSTR + fk8;          // N-tile 0
  const __hip_bfloat16* wb1 = wsl + (16 + frow) * WSTR + fk8;   // N-tile 1
  unsigned budget = 1u << 24;

#pragma unroll 1
  for (int t = 0; t < 512; ++t) {
    // ---- dataflow poll: wave 0, lane i <-> producer block i ----
    if (tid < 64 && (t > 0 || L > 0)) {
      const unsigned tg = (unsigned)t;
      while (budget) {
        bool ok = true;
        if constexpr (L == 1) {
          ok &= (ldf(fl, 0, tid) >= tg + 1);
        } else if constexpr (L == 2) {
          ok &= (ldf(fl, 0, tid) >= tg + 1);
          ok &= (ldf(fl, 1, tid) >= tg + 1);
        } else if constexpr (L == 3) {
          const unsigned m0 = (t + 2 > 512) ? 512u : tg + 2;
          ok &= (ldf(fl, 0, tid) >= m0);
          ok &= (ldf(fl, 1, tid) >= tg + 1);
          ok &= (ldf(fl, 2, tid) >= tg + 1);
        }
        if (t > 0) ok &= (ldf(fl, L, tid) >= tg);
        if (__all(ok)) break;
        --budget;
      }
    }
    __syncthreads();

    // ---- A bases ----
    const size_t rowx = (size_t)(t * 64 + m);
    const __hip_bfloat16* b1p = seg1 + rowx * LDA1 + fk8;
    const __hip_bfloat16* b2p = (KS2 > 0) ? (seg2 + rowx * LDA2 + fk8) : seg1;
    const __hip_bfloat16* bhp = t ? (hseq + (((size_t)(t - 1) * 64 + m) << 9) + fk8)
                                  : (h0b + ((size_t)m << 9) + fk8);

    f32x4 acc0 = {0.f, 0.f, 0.f, 0.f}, acc1 = {0.f, 0.f, 0.f, 0.f};
    short8 ab[3][16];

    // counted-vmcnt pipelined rounds (loads stay in flight across MFMA)
    issue_round<0, NKS, KS1, KS2, S1H, S2H>(ab[0], b1p, b2p, bhp);
    if constexpr (NR > 1) issue_round<1, NKS, KS1, KS2, S1H, S2H>(ab[1], b1p, b2p, bhp);
    waitv<C1>(); __builtin_amdgcn_sched_barrier(0);
    mfma_round<0, NKS>(ab[0], wb0, wb1, acc0, acc1);
    if constexpr (NR > 2) issue_round<2, NKS, KS1, KS2, S1H, S2H>(ab[2], b1p, b2p, bhp);
    if constexpr (NR > 1) {
      waitv<C2>(); __builtin_amdgcn_sched_barrier(0);
      mfma_round<1, NKS>(ab[1], wb0, wb1, acc0, acc1);
    }
    if constexpr (NR > 2) {
      waitv<0>(); __builtin_amdgcn_sched_barrier(0);
      mfma_round<2, NKS>(ab[2], wb0, wb1, acc0, acc1);
    }

    // epilogue: C col = lane&15 (+16 for tile 1), row = w*16 + (lane>>4)*4 + j
    {
      const int crow = (w << 4) + ((lane >> 4) << 2);
#pragma unroll
      for (int j = 0; j < 4; ++j) {
        gbuf[crow + j][frow]      = acc0[j] + bs[frow];
        gbuf[crow + j][16 + frow] = acc1[j] + bs[16 + frow];
      }
    }
    __syncthreads();
    // elementwise: thread -> (batch row bb, unit pair u2,u2+1); gates i,f,g,o
    {
      const int bb = tid >> 2, u2 = (tid & 3) << 1;
      unsigned packed = 0;
      float dhv[2], dcv[2];
#pragma unroll
      for (int q = 0; q < 2; ++q) {
        const int u = u2 + q;
        float gi = gbuf[bb][u],      gf = gbuf[bb][8 + u];
        float gg = gbuf[bb][16 + u], go = gbuf[bb][24 + u];
        float cn = sigm_f(gf) * cst[bb][u] + sigm_f(gi) * tanh_f(gg);
        float hn = sigm_f(go) * tanh_f(cn);
        cst[bb][u] = cn;
        __hip_bfloat16 hb = __float2bfloat16(hn);
        packed |= ((unsigned)*(unsigned short*)&hb) << (16 * q);
        dhv[q] = hn; dcv[q] = cn;
      }
      stg32_cc(hseq + (((size_t)(t * 64 + bb)) << 9) + u0 + u2, packed);
      if (t == 511) {
        dh[(size_t)bb * 512 + u0 + u2]     = dhv[0];
        dh[(size_t)bb * 512 + u0 + u2 + 1] = dhv[1];
        dc[(size_t)bb * 512 + u0 + u2]     = dcv[0];
        dc[(size_t)bb * 512 + u0 + u2 + 1] = dcv[1];
      }
    }
    waitv<0>();        // all coherent h stores acked at the coherence point
    __syncthreads();   // every wave drained before the flag post
    if (tid == 0)
      __hip_atomic_store(fl + (L * 64 + n) * 16, (unsigned)(t + 1),
                         __ATOMIC_RELAXED, __HIP_MEMORY_SCOPE_AGENT);
  }
}

__global__ __launch_bounds__(256, 1) void arm_fused_kernel(FusedParams p)
{
  __shared__ __align__(16) __hip_bfloat16 wsl[32 * WSTR];   // 96.5 KB
  __shared__ float gbuf[64][33];                            // 8.4 KB
  __shared__ float cst[64][9];                              // 2.25 KB
  __shared__ float bs[32];

  const int blk = blockIdx.x;
  const int xcd = blk & 7;
  const int l   = xcd >> 1;
  const int n   = ((blk >> 3) << 1) | (xcd & 1);
  const int u0  = n << 3;

  switch (l) {
    case 0: run_layer< 96, 96,   0,   0, false, false, 0>(p.seg1[0], p.seg2[0],
              p.wihp[0], p.whhb[0], p.bsum[0], p.h0b, p.c0, p.hout[0],
              p.dh[0], p.dc[0], p.flags, u0, wsl, gbuf, cst, bs); break;
    case 1: run_layer<512, 512, 96,  96, true, false, 1>(p.seg1[1], p.seg2[1],
              p.wihp[1], p.whhb[1], p.bsum[1], p.h0b, p.c0, p.hout[1],
              p.dh[1], p.dc[1], p.flags, u0, wsl, gbuf, cst, bs); break;
    case 2: run_layer<512, 512, 512, 512, true, true, 2>(p.seg1[2], p.seg2[2],
              p.wihp[2], p.whhb[2], p.bsum[2], p.h0b, p.c0, p.hout[2],
              p.dh[2], p.dc[2], p.flags, u0, wsl, gbuf, cst, bs); break;
    default: run_layer<512, 512, 512, 512, true, true, 3>(p.seg1[3], p.seg2[3],
              p.wihp[3], p.whhb[3], p.bsum[3], p.h0b, p.c0, p.hout[3],
              p.dh[3], p.dc[3], p.flags, u0, wsl, gbuf, cst, bs); break;
  }
}

// ---------------- final projection: out = [h3,h4] @ Wout^T + bout, sigmoid(:2)
__global__ __launch_bounds__(256) void arm_out_kernel(
    const __hip_bfloat16* __restrict__ h3b, const __hip_bfloat16* __restrict__ h4b,
    const float* __restrict__ Wout, const float* __restrict__ bout,
    float* __restrict__ out)
{
  __shared__ float w_s[16][1025];
  __shared__ __hip_bfloat16 a_s[16][1032];
  __shared__ float bo[16];
  const int tid = threadIdx.x;
  for (int i = tid; i < 16 * 1024; i += 256) {
    int n = i >> 10, k = i & 1023;
    w_s[n][k] = Wout[i];
  }
  if (tid < 16) bo[tid] = bout[tid];
  const int rb = blockIdx.x * 16;
  for (int i = tid; i < 16 * 512; i += 256) {
    int r = i >> 9, k = i & 511;
    a_s[r][k]       = h3b[(((size_t)(rb + r)) << 9) + k];
    a_s[r][512 + k] = h4b[(((size_t)(rb + r)) << 9) + k];
  }
  __syncthreads();
  const int r = tid >> 4, n = tid & 15;
  float acc = bo[n];
  for (int k = 0; k < 1024; ++k)
    acc += __bfloat162float(a_s[r][k]) * w_s[n][k];
  const int ri = rb + r, t = ri >> 6, b = ri & 63;
  if (n < 2) acc = sigm_f(acc);
  out[((size_t)(b * 512 + t)) * 16 + n] = acc;
}

extern "C" void kernel_launch(void* const* d_in, const int* in_sizes, int n_in,
                              void* d_out, int out_size, void* d_ws, size_t ws_size,
                              hipStream_t stream) {
  (void)in_sizes; (void)n_in; (void)out_size; (void)ws_size;
  const float* stat = (const float*)d_in[0];
  const float* rec  = (const float*)d_in[1];
  const float* Wh1 = (const float*)d_in[2];  const float* bh1 = (const float*)d_in[3];
  const float* Wh2 = (const float*)d_in[4];  const float* bh2 = (const float*)d_in[5];
  const float* Wh3 = (const float*)d_in[6];  const float* bh3 = (const float*)d_in[7];
  const float* Wc1 = (const float*)d_in[8];  const float* bc1 = (const float*)d_in[9];
  const float* Wc2 = (const float*)d_in[10]; const float* bc2 = (const float*)d_in[11];
  const float* Wc3 = (const float*)d_in[12]; const float* bc3 = (const float*)d_in[13];
  const float* Wih[4] = {(const float*)d_in[14], (const float*)d_in[18],
                         (const float*)d_in[22], (const float*)d_in[26]};
  const float* Whh[4] = {(const float*)d_in[15], (const float*)d_in[19],
                         (const float*)d_in[23], (const float*)d_in[27]};
  const float* bih[4] = {(const float*)d_in[16], (const float*)d_in[20],
                         (const float*)d_in[24], (const float*)d_in[28]};
  const float* bhh[4] = {(const float*)d_in[17], (const float*)d_in[21],
                         (const float*)d_in[25], (const float*)d_in[29]};
  const float* Wout = (const float*)d_in[30];
  const float* bout = (const float*)d_in[31];
  float* out = (float*)d_out;

  char* ws = (char*)d_ws;
  size_t off = 0;
  auto take = [&](size_t bytes) -> void* {
    void* p = ws + off;
    off = (off + bytes + 255) & ~(size_t)255;
    return p;
  };
  __hip_bfloat16* h0b   = (__hip_bfloat16*)take((size_t)64 * 512 * 2);
  float*          c0    = (float*)take((size_t)64 * 512 * 4);
  __hip_bfloat16* xcatb = (__hip_bfloat16*)take((size_t)TBROWS * 96 * 2);
  __hip_bfloat16* hs1   = (__hip_bfloat16*)take((size_t)TBROWS * 512 * 2);
  __hip_bfloat16* hs2   = (__hip_bfloat16*)take((size_t)TBROWS * 512 * 2);
  __hip_bfloat16* hs3   = (__hip_bfloat16*)take((size_t)TBROWS * 512 * 2);
  static const int Kp_[4] = {96, 608, 1024, 1024};
  static const int Ks_[4] = {80, 592, 1024, 1024};
  __hip_bfloat16* wihp[4]; __hip_bfloat16* whhb[4]; float* bsum[4];
  for (int l = 0; l < 4; ++l) {
    wihp[l] = (__hip_bfloat16*)take((size_t)2048 * Kp_[l] * 2);
    whhb[l] = (__hip_bfloat16*)take((size_t)2048 * 512 * 2);
    bsum[l] = (float*)take(2048 * 4);
  }
  unsigned* flags = (unsigned*)take(256 * 64);

  hipMemsetAsync(flags, 0, 256 * 64, stream);
  arm_mlp_kernel<<<64, 512, 0, stream>>>(stat, Wh1, bh1, Wh2, bh2, Wh3, bh3,
                                         Wc1, bc1, Wc2, bc2, Wc3, bc3, h0b, c0);
  arm_xcat_kernel<<<1024, 256, 0, stream>>>(stat, rec, xcatb);
  for (int l = 0; l < 4; ++l) {
    arm_cvtpad_kernel<<<512, 256, 0, stream>>>(Wih[l], wihp[l], 2048, Ks_[l], Kp_[l]);
    arm_cvtpad_kernel<<<512, 256, 0, stream>>>(Whh[l], whhb[l], 2048, 512, 512);
    arm_bsum_kernel<<<8, 256, 0, stream>>>(bih[l], bhh[l], bsum[l], 2048);
  }

  float* dbase = out + (size_t)64 * 512 * 16;
  FusedParams p;
  // L1: x(96) -> hs1          L2: [h1(512), x(96)] -> hs2
  // L3: [h1,h2] -> hs3        L4: [h2,h3] -> hs1 (WAR-safe via f0>=t+2 wait)
  p.seg1[0] = xcatb; p.seg2[0] = nullptr;
  p.seg1[1] = hs1;   p.seg2[1] = xcatb;
  p.seg1[2] = hs1;   p.seg2[2] = hs2;
  p.seg1[3] = hs2;   p.seg2[3] = hs3;
  for (int l = 0; l < 4; ++l) { p.wihp[l] = wihp[l]; p.whhb[l] = whhb[l]; p.bsum[l] = bsum[l]; }
  p.h0b = h0b; p.c0 = c0;
  p.hout[0] = hs1; p.hout[1] = hs2; p.hout[2] = hs3; p.hout[3] = hs1;
  for (int l = 0; l < 4; ++l) {
    p.dh[l] = dbase + l * 65536;
    p.dc[l] = dbase + l * 65536 + 32768;
  }
  p.flags = flags;

  arm_fused_kernel<<<256, 256, 0, stream>>>(p);
  arm_out_kernel<<<2048, 256, 0, stream>>>(hs3, hs1, Wout, bout, out);
}